// Round 6
// baseline (67.134 us; speedup 1.0000x reference)
//
#include <hip/hip_runtime.h>
#include <hip/hip_bf16.h>

// Problem constants (reference: K=512, D=128, N=8192)
#define KC 512
#define DD 128
#define NP 8192

// ws layout (bytes):
//   [0,      2KB)   sumc2 (512 f32)
//   [4096,   +256KB) CkT (128 x 512 f32)
//   [266240, +32KB) idx   (8192 i32)  per-point argmin
//   [299008, +32KB) order (8192 i32)  points bucketed by cluster
//   [331776, +2KB)  cnts  (512 i32)
//   [333824, +2KB)  offs  (512 i32)

// ---------------- prep: transpose Ck -> CkT, sumc2 ----------------
__global__ __launch_bounds__(256) void kprep(const float* __restrict__ Ck,
                                             float* __restrict__ CkT,
                                             float* __restrict__ sumc2) {
    const int b = blockIdx.x;
    const int t = threadIdx.x;
    if (b < 64) {
        const float4 v = *(const float4*)(Ck + b * 1024 + t * 4);
        const int k = b * 8 + (t >> 5);
        const int d = (t & 31) * 4;
        CkT[(d + 0) * KC + k] = v.x;
        CkT[(d + 1) * KC + k] = v.y;
        CkT[(d + 2) * KC + k] = v.z;
        CkT[(d + 3) * KC + k] = v.w;
    } else {
        #pragma unroll
        for (int c = 0; c < 2; ++c) {
            const int k = t + c * 256;
            const float4* row = (const float4*)(Ck + k * DD);
            float s = 0.f;
            #pragma unroll
            for (int i = 0; i < 32; ++i) {
                const float4 v = row[i];
                s += v.x * v.x + v.y * v.y + v.z * v.z + v.w * v.w;
            }
            sumc2[k] = s;
        }
    }
}

// ---------------- assign: distances + argmin -> idx[p] ----------------
// Round-4 structure (fastest measured GEMM): 1024 blocks x 128 thr (2 waves).
// Block: 8 points; wave h owns centroid half h; lane owns 4+4 cents (contiguous
// 16B in CkT row -> coalesced dwordx4 from L2, reg-staged, no loop barriers).
// Single ascending-d fmaf chain per (p,cent) (absmax 4e-3 measured).
__global__ __launch_bounds__(128) void kassign(const float* __restrict__ X,
                                               const float* __restrict__ CkT,
                                               const float* __restrict__ sumc2,
                                               int* __restrict__ idxout) {
    __shared__ __align__(16) float xs[8 * DD];   // 4 KB
    __shared__ float bvx[2][8];
    __shared__ int   bix[2][8];

    const int tid  = threadIdx.x;
    const int lane = tid & 63;
    const int h    = tid >> 6;
    const int p0   = blockIdx.x * 8;

    {
        const float4* Xv = (const float4*)(X + p0 * DD);
        float4* xv = (float4*)xs;
        xv[tid]       = Xv[tid];
        xv[tid + 128] = Xv[tid + 128];
    }
    __syncthreads();

    const float* cp = CkT + h * 256 + 4 * lane;  // this thread's 4-cent column

    float4 cn[4], cc[4];
    #pragma unroll
    for (int dd = 0; dd < 4; ++dd) cn[dd] = *(const float4*)(cp + dd * KC);

    float acc[8][4];
    #pragma unroll
    for (int p = 0; p < 8; ++p)
        #pragma unroll
        for (int j = 0; j < 4; ++j) acc[p][j] = 0.f;

    #pragma unroll 4
    for (int t = 0; t < 32; ++t) {
        #pragma unroll
        for (int dd = 0; dd < 4; ++dd) cc[dd] = cn[dd];
        if (t < 31) {
            #pragma unroll
            for (int dd = 0; dd < 4; ++dd)
                cn[dd] = *(const float4*)(cp + ((t + 1) * 4 + dd) * KC);
        }
        float4 xf[8];
        #pragma unroll
        for (int p = 0; p < 8; ++p)
            xf[p] = *(const float4*)&xs[p * DD + t * 4];   // uniform -> LDS broadcast
        #pragma unroll
        for (int dd = 0; dd < 4; ++dd) {
            #pragma unroll
            for (int p = 0; p < 8; ++p) {
                const float xv = (&xf[p].x)[dd];
                acc[p][0] = fmaf(xv, cc[dd].x, acc[p][0]);
                acc[p][1] = fmaf(xv, cc[dd].y, acc[p][1]);
                acc[p][2] = fmaf(xv, cc[dd].z, acc[p][2]);
                acc[p][3] = fmaf(xv, cc[dd].w, acc[p][3]);
            }
        }
    }

    // per-thread argmin over its 4 centroids (ascending index, strict <)
    float bestv[8];
    int   besti[8];
    #pragma unroll
    for (int p = 0; p < 8; ++p) { bestv[p] = 3.4e38f; besti[p] = 0; }
    const float4 s2v = *(const float4*)(sumc2 + h * 256 + 4 * lane);
    #pragma unroll
    for (int j = 0; j < 4; ++j) {
        const int cent = h * 256 + 4 * lane + j;
        const float s2 = (&s2v.x)[j];
        #pragma unroll
        for (int p = 0; p < 8; ++p) {
            const float v = fmaf(-2.f, acc[p][j], s2);   // monotonic proxy for d2
            if (v < bestv[p]) { bestv[p] = v; besti[p] = cent; }
        }
    }
    // wave butterfly, tie-break on smaller index (jnp.argmin = first min)
    #pragma unroll
    for (int off = 1; off < 64; off <<= 1) {
        #pragma unroll
        for (int p = 0; p < 8; ++p) {
            const float ov = __shfl_xor(bestv[p], off);
            const int   oi = __shfl_xor(besti[p], off);
            if (ov < bestv[p] || (ov == bestv[p] && oi < besti[p])) {
                bestv[p] = ov; besti[p] = oi;
            }
        }
    }
    if (lane == 0) {
        #pragma unroll
        for (int p = 0; p < 8; ++p) { bvx[h][p] = bestv[p]; bix[h][p] = besti[p]; }
    }
    __syncthreads();
    if (tid < 8) {
        const float v0 = bvx[0][tid], v1 = bvx[1][tid];
        idxout[p0 + tid] = (v1 < v0) ? bix[1][tid] : bix[0][tid];  // tie -> lower idx
    }
}

// ---------------- order: histogram + prefix + bucket (1 block) ----------------
// Also writes nItems (as float) directly -- no out-zeroing kernel needed.
__global__ __launch_bounds__(512) void korder(const int* __restrict__ idx,
                                              int* __restrict__ order,
                                              int* __restrict__ cnts,
                                              int* __restrict__ offs,
                                              float* __restrict__ out) {
    __shared__ int hist[KC];
    __shared__ int scan[KC];
    __shared__ int cur[KC];
    const int t = threadIdx.x;

    hist[t] = 0;
    __syncthreads();

    int myidx[16];
    #pragma unroll
    for (int i = 0; i < 16; ++i) {
        myidx[i] = idx[t + 512 * i];
        atomicAdd(&hist[myidx[i]], 1);          // LDS atomic
    }
    __syncthreads();

    const int c = hist[t];
    out[KC * DD + t] = (float)c;                // nItems
    cnts[t] = c;

    // inclusive Hillis-Steele scan -> exclusive offsets
    scan[t] = c;
    __syncthreads();
    for (int off = 1; off < KC; off <<= 1) {
        const int add = (t >= off) ? scan[t - off] : 0;
        __syncthreads();
        scan[t] += add;
        __syncthreads();
    }
    const int excl = scan[t] - c;
    offs[t] = excl;
    cur[t]  = excl;
    __syncthreads();

    #pragma unroll
    for (int i = 0; i < 16; ++i) {
        const int p = t + 512 * i;
        const int slot = atomicAdd(&cur[myidx[i]], 1);   // LDS atomic
        order[slot] = p;
    }
}

// ---------------- gather: out[k][:] = sum of member rows ----------------
// Block k (128 threads, thread = dim d): coalesced 512B row reads; each X row
// is read exactly once across the grid. Plain stores, no atomics.
__global__ __launch_bounds__(128) void kgather(const float* __restrict__ X,
                                               const int* __restrict__ order,
                                               const int* __restrict__ cnts,
                                               const int* __restrict__ offs,
                                               float* __restrict__ out) {
    const int k = blockIdx.x;
    const int d = threadIdx.x;
    const int cnt = cnts[k];
    const int off = offs[k];

    float s0 = 0.f, s1 = 0.f, s2 = 0.f, s3 = 0.f;
    int i = 0;
    for (; i + 4 <= cnt; i += 4) {
        const int pa = order[off + i + 0];
        const int pb = order[off + i + 1];
        const int pc = order[off + i + 2];
        const int pd = order[off + i + 3];
        s0 += X[pa * DD + d];
        s1 += X[pb * DD + d];
        s2 += X[pc * DD + d];
        s3 += X[pd * DD + d];
    }
    for (; i < cnt; ++i) s0 += X[order[off + i] * DD + d];
    out[k * DD + d] = (s0 + s1) + (s2 + s3);
}

extern "C" void kernel_launch(void* const* d_in, const int* in_sizes, int n_in,
                              void* d_out, int out_size, void* d_ws, size_t ws_size,
                              hipStream_t stream) {
    const float* locF = (const float*)d_in[0];
    const float* Ck   = (const float*)d_in[1];
    float* out   = (float*)d_out;
    char*  ws    = (char*)d_ws;
    float* sumc2 = (float*)(ws);
    float* CkT   = (float*)(ws + 4096);
    int*   idx   = (int*)(ws + 266240);
    int*   order = (int*)(ws + 299008);
    int*   cnts  = (int*)(ws + 331776);
    int*   offs  = (int*)(ws + 333824);

    hipLaunchKernelGGL(kprep,   dim3(65),   dim3(256), 0, stream, Ck, CkT, sumc2);
    hipLaunchKernelGGL(kassign, dim3(1024), dim3(128), 0, stream, locF, CkT, sumc2, idx);
    hipLaunchKernelGGL(korder,  dim3(1),    dim3(512), 0, stream, idx, order, cnts, offs, out);
    hipLaunchKernelGGL(kgather, dim3(512),  dim3(128), 0, stream, locF, order, cnts, offs, out);
}

// Round 7
// 56.641 us; speedup vs baseline: 1.1853x; 1.1853x over previous
//
#include <hip/hip_runtime.h>
#include <hip/hip_bf16.h>

// Problem constants (reference: K=512, D=128, N=8192)
#define KC 512
#define DD 128
#define NP 8192

// ws layout (bytes), all 4KB-aligned:
//   [0,      2KB)    sumc2    (512 f32)
//   [4096,   266240) CkT      (128 x 512 f32)
//   [266240, 299008) idx      (8192 i32)   per-point argmin
//   [299008, 331776) rank2    (8192 i32)   rank within (cluster, group)
//   [331776, 462848) cnts2    (512 x 64 i32) split counters
//   [462848, 593920) offsflat (512 x 64 i32) exclusive scan of cnts2
//   [593920, 659456) sorted   (8192 int2)  (point, cluster) bucketed by cluster

// ---------------- prep: transpose, sumc2, zero out-sums & cnts2 ----------------
__global__ __launch_bounds__(256) void kprep(const float* __restrict__ Ck,
                                             float* __restrict__ CkT,
                                             float* __restrict__ sumc2,
                                             float* __restrict__ out,
                                             int* __restrict__ cnts2) {
    const int b = blockIdx.x;
    const int t = threadIdx.x;
    if (b < 64) {
        const float4 v = *(const float4*)(Ck + b * 1024 + t * 4);
        const int k = b * 8 + (t >> 5);
        const int d = (t & 31) * 4;
        CkT[(d + 0) * KC + k] = v.x;
        CkT[(d + 1) * KC + k] = v.y;
        CkT[(d + 2) * KC + k] = v.z;
        CkT[(d + 3) * KC + k] = v.w;
    } else if (b == 64) {
        #pragma unroll
        for (int c = 0; c < 2; ++c) {
            const int k = t + c * 256;
            const float4* row = (const float4*)(Ck + k * DD);
            float s = 0.f;
            #pragma unroll
            for (int i = 0; i < 32; ++i) {
                const float4 v = row[i];
                s += v.x * v.x + v.y * v.y + v.z * v.z + v.w * v.w;
            }
            sumc2[k] = s;
        }
    } else if (b < 97) {
        // zero out sums region: 65536 floats over 32 blocks
        float* dst = out + (b - 65) * 2048;
        #pragma unroll
        for (int i = 0; i < 8; ++i) dst[t + 256 * i] = 0.f;
    } else {
        // zero cnts2: 32768 ints over 16 blocks
        int* dst = cnts2 + (b - 97) * 2048;
        #pragma unroll
        for (int i = 0; i < 8; ++i) dst[t + 256 * i] = 0;
    }
}

// ---------------- assign: distances + argmin -> idx[p], rank2[p] ----------------
// 1024 blocks x 128 thr (2 waves). Block: 8 points; wave h owns centroid half h;
// lane owns 4 cents (contiguous 16B in CkT row -> coalesced dwordx4 from L2,
// reg-staged, no loop barriers). Single ascending-d fmaf chain (absmax 4e-3).
__global__ __launch_bounds__(128) void kassign(const float* __restrict__ X,
                                               const float* __restrict__ CkT,
                                               const float* __restrict__ sumc2,
                                               int* __restrict__ idxout,
                                               int* __restrict__ rank2,
                                               int* __restrict__ cnts2) {
    __shared__ __align__(16) float xs[8 * DD];   // 4 KB
    __shared__ float bvx[2][8];
    __shared__ int   bix[2][8];

    const int tid  = threadIdx.x;
    const int lane = tid & 63;
    const int h    = tid >> 6;
    const int p0   = blockIdx.x * 8;

    {
        const float4* Xv = (const float4*)(X + p0 * DD);
        float4* xv = (float4*)xs;
        xv[tid]       = Xv[tid];
        xv[tid + 128] = Xv[tid + 128];
    }
    __syncthreads();

    const float* cp = CkT + h * 256 + 4 * lane;  // this thread's 4-cent column

    float4 cn[4], cc[4];
    #pragma unroll
    for (int dd = 0; dd < 4; ++dd) cn[dd] = *(const float4*)(cp + dd * KC);

    float acc[8][4];
    #pragma unroll
    for (int p = 0; p < 8; ++p)
        #pragma unroll
        for (int j = 0; j < 4; ++j) acc[p][j] = 0.f;

    #pragma unroll 4
    for (int t = 0; t < 32; ++t) {
        #pragma unroll
        for (int dd = 0; dd < 4; ++dd) cc[dd] = cn[dd];
        if (t < 31) {
            #pragma unroll
            for (int dd = 0; dd < 4; ++dd)
                cn[dd] = *(const float4*)(cp + ((t + 1) * 4 + dd) * KC);
        }
        float4 xf[8];
        #pragma unroll
        for (int p = 0; p < 8; ++p)
            xf[p] = *(const float4*)&xs[p * DD + t * 4];   // uniform -> LDS broadcast
        #pragma unroll
        for (int dd = 0; dd < 4; ++dd) {
            #pragma unroll
            for (int p = 0; p < 8; ++p) {
                const float xv = (&xf[p].x)[dd];
                acc[p][0] = fmaf(xv, cc[dd].x, acc[p][0]);
                acc[p][1] = fmaf(xv, cc[dd].y, acc[p][1]);
                acc[p][2] = fmaf(xv, cc[dd].z, acc[p][2]);
                acc[p][3] = fmaf(xv, cc[dd].w, acc[p][3]);
            }
        }
    }

    // per-thread argmin over its 4 centroids (ascending index, strict <)
    float bestv[8];
    int   besti[8];
    #pragma unroll
    for (int p = 0; p < 8; ++p) { bestv[p] = 3.4e38f; besti[p] = 0; }
    const float4 s2v = *(const float4*)(sumc2 + h * 256 + 4 * lane);
    #pragma unroll
    for (int j = 0; j < 4; ++j) {
        const int cent = h * 256 + 4 * lane + j;
        const float s2 = (&s2v.x)[j];
        #pragma unroll
        for (int p = 0; p < 8; ++p) {
            const float v = fmaf(-2.f, acc[p][j], s2);   // monotonic proxy for d2
            if (v < bestv[p]) { bestv[p] = v; besti[p] = cent; }
        }
    }
    // wave butterfly, tie-break on smaller index (jnp.argmin = first min)
    #pragma unroll
    for (int off = 1; off < 64; off <<= 1) {
        #pragma unroll
        for (int p = 0; p < 8; ++p) {
            const float ov = __shfl_xor(bestv[p], off);
            const int   oi = __shfl_xor(besti[p], off);
            if (ov < bestv[p] || (ov == bestv[p] && oi < besti[p])) {
                bestv[p] = ov; besti[p] = oi;
            }
        }
    }
    if (lane == 0) {
        #pragma unroll
        for (int p = 0; p < 8; ++p) { bvx[h][p] = bestv[p]; bix[h][p] = besti[p]; }
    }
    __syncthreads();
    if (tid < 8) {
        const float v0 = bvx[0][tid], v1 = bvx[1][tid];
        const int c = (v1 < v0) ? bix[1][tid] : bix[0][tid];  // tie -> lower idx
        const int p = p0 + tid;
        idxout[p] = c;
        // 64-way-split rank: hot-cluster contention <= 1024/64*8 = 128 per address
        rank2[p] = atomicAdd(&cnts2[c * 64 + (blockIdx.x & 63)], 1);
    }
}

// ---------------- scan + scatter (1 block x 1024) ----------------
// Flat exclusive scan of cnts2[512*64] (thread t owns cluster t's 64 counters
// -> writes nItems directly), then buckets points: sorted[off+rank] = (p,c).
__global__ __launch_bounds__(1024) void kscan(const int* __restrict__ cnts2,
                                              const int* __restrict__ idx,
                                              const int* __restrict__ rank2,
                                              int* __restrict__ offsflat,
                                              int2* __restrict__ sorted,
                                              float* __restrict__ out) {
    __shared__ int sex[1024];
    const int t = threadIdx.x;

    int arr[32];
    {
        const int4* src = (const int4*)cnts2 + t * 8;
        #pragma unroll
        for (int i = 0; i < 8; ++i) {
            const int4 v = src[i];
            arr[4 * i + 0] = v.x; arr[4 * i + 1] = v.y;
            arr[4 * i + 2] = v.z; arr[4 * i + 3] = v.w;
        }
    }
    int loc[32];
    int tot = 0;
    #pragma unroll
    for (int i = 0; i < 32; ++i) { loc[i] = tot; tot += arr[i]; }

    // Hillis-Steele inclusive scan over 1024 thread-totals
    sex[t] = tot;
    __syncthreads();
    for (int off = 1; off < 1024; off <<= 1) {
        const int a = (t >= off) ? sex[t - off] : 0;
        __syncthreads();
        sex[t] += a;
        __syncthreads();
    }
    const int excl = sex[t] - tot;

    // per-element exclusive offsets (int4 stores)
    {
        int4* dst = (int4*)offsflat + t * 8;
        #pragma unroll
        for (int i = 0; i < 8; ++i)
            dst[i] = make_int4(excl + loc[4 * i + 0], excl + loc[4 * i + 1],
                               excl + loc[4 * i + 2], excl + loc[4 * i + 3]);
    }

    // nItems: thread t (<512) owns cluster t exactly (64 counters = its chunk)
    __syncthreads();
    sex[t] = excl;
    __syncthreads();
    if (t < 512) {
        const int start = sex[2 * t];
        const int end   = (t == 511) ? NP : sex[2 * t + 2];
        out[KC * DD + t] = (float)(end - start);
    }

    // scatter: offsflat stores drained by the syncthreads above (same CU/L2)
    __syncthreads();
    #pragma unroll
    for (int i = 0; i < 8; ++i) {
        const int p = t + 1024 * i;
        const int c = idx[p];
        const int g = (p >> 3) & 63;            // kassign block's group
        const int s0 = offsflat[c * 64 + g] + rank2[p];
        sorted[s0] = make_int2(p, c);
    }
}

// ---------------- gather: fixed 16 sorted slots per block ----------------
// Thread = dim d. 16 independent row loads in flight; one atomic row-add per
// cluster-run (total runs <= 1023 across the grid -> no hot straggler).
__global__ __launch_bounds__(128) void kgather(const float* __restrict__ X,
                                               const int2* __restrict__ sorted,
                                               float* __restrict__ out) {
    const int d  = threadIdx.x;
    const int s0 = blockIdx.x * 16;

    int2 pc[16];
    #pragma unroll
    for (int i = 0; i < 16; ++i) pc[i] = sorted[s0 + i];

    float xr[16];
    #pragma unroll
    for (int i = 0; i < 16; ++i) xr[i] = X[pc[i].x * DD + d];

    float sum = 0.f;
    #pragma unroll
    for (int i = 0; i < 15; ++i) {
        sum += xr[i];
        if (pc[i + 1].y != pc[i].y) {           // run boundary (wave-uniform)
            atomicAdd(&out[pc[i].y * DD + d], sum);
            sum = 0.f;
        }
    }
    sum += xr[15];
    atomicAdd(&out[pc[15].y * DD + d], sum);
}

extern "C" void kernel_launch(void* const* d_in, const int* in_sizes, int n_in,
                              void* d_out, int out_size, void* d_ws, size_t ws_size,
                              hipStream_t stream) {
    const float* locF = (const float*)d_in[0];
    const float* Ck   = (const float*)d_in[1];
    float* out      = (float*)d_out;
    char*  ws       = (char*)d_ws;
    float* sumc2    = (float*)(ws);
    float* CkT      = (float*)(ws + 4096);
    int*   idx      = (int*)(ws + 266240);
    int*   rank2    = (int*)(ws + 299008);
    int*   cnts2    = (int*)(ws + 331776);
    int*   offsflat = (int*)(ws + 462848);
    int2*  sorted   = (int2*)(ws + 593920);

    hipLaunchKernelGGL(kprep,   dim3(113),  dim3(256),  0, stream, Ck, CkT, sumc2, out, cnts2);
    hipLaunchKernelGGL(kassign, dim3(1024), dim3(128),  0, stream, locF, CkT, sumc2, idx, rank2, cnts2);
    hipLaunchKernelGGL(kscan,   dim3(1),    dim3(1024), 0, stream, cnts2, idx, rank2, offsflat, sorted, out);
    hipLaunchKernelGGL(kgather, dim3(512),  dim3(128),  0, stream, locF, sorted, out);
}